// Round 3
// baseline (299.509 us; speedup 1.0000x reference)
//
#include <hip/hip_runtime.h>
#include <hip/hip_bf16.h>

#define NN 8192
#define DD 128
#define BB 4096

#define ROWS_PER_BLOCK 128   // 4 waves * 2 rowfrags * 16
#define COLSPLIT 32
#define COLS_PER_BLOCK (NN / COLSPLIT)   // 256
#define COL_ITERS (COLS_PER_BLOCK / 64)  // 4

typedef __attribute__((ext_vector_type(8))) short short8;
typedef __attribute__((ext_vector_type(4))) float f32x4;

// ---- kernel 1: normalize rows -> bf16, pos dot, self dot, zero accums -----
// One block = row pair (r, r+BB). Wave 0 handles r (from z_i), wave 1 r+BB.
__global__ __launch_bounds__(128) void prep_kernel(
    const float* __restrict__ zi, const float* __restrict__ zj,
    __hip_bfloat16* __restrict__ zn, float* __restrict__ posh,
    float* __restrict__ sd, float* __restrict__ rowsum,
    int* __restrict__ rowcnt) {
  int r0 = blockIdx.x;
  int w = threadIdx.x >> 6;
  int lane = threadIdx.x & 63;
  int row = r0 + w * BB;
  const float* src = (w ? zj : zi) + (size_t)r0 * DD;
  float2 v = *reinterpret_cast<const float2*>(src + lane * 2);
  float ss = v.x * v.x + v.y * v.y;
  #pragma unroll
  for (int m = 1; m < 64; m <<= 1) ss += __shfl_xor(ss, m, 64);
  float inv = 1.0f / fmaxf(sqrtf(ss), 1e-8f);
  __hip_bfloat16 b0 = __float2bfloat16(v.x * inv);
  __hip_bfloat16 b1 = __float2bfloat16(v.y * inv);
  *reinterpret_cast<__hip_bfloat162*>(zn + (size_t)row * DD + lane * 2) =
      __hip_bfloat162{b0, b1};
  // bf16-rounded values (consistent with what main_kernel's MFMA consumes)
  float f0 = __bfloat162float(b0), f1 = __bfloat162float(b1);
  float sq = f0 * f0 + f1 * f1;
  __shared__ float sb[2][DD];
  sb[w][2 * lane] = f0;
  sb[w][2 * lane + 1] = f1;
  __syncthreads();
  float o0 = sb[w ^ 1][2 * lane], o1 = sb[w ^ 1][2 * lane + 1];
  float dp = f0 * o0 + f1 * o1;
  #pragma unroll
  for (int m = 1; m < 64; m <<= 1) {
    sq += __shfl_xor(sq, m, 64);
    dp += __shfl_xor(dp, m, 64);
  }
  if (lane == 0) {
    sd[row] = sq;
    posh[row] = dp;     // symmetric: same value for both rows of the pair
    rowsum[row] = 0.0f;
    rowcnt[row] = 0;
  }
}

// ---- kernel 2: fused sim GEMM + exp-rowsum + count ------------------------
__global__ __launch_bounds__(256, 8) void main_kernel(
    const __hip_bfloat16* __restrict__ zn, const float* __restrict__ posh,
    float* __restrict__ rowsum, int* __restrict__ rowcnt) {
  int w = threadIdx.x >> 6;
  int lane = threadIdx.x & 63;
  int lo = lane & 15, hi = lane >> 4;
  int rowBase = blockIdx.x * ROWS_PER_BLOCK;
  int colBase = blockIdx.y * COLS_PER_BLOCK;

  const short* znS = reinterpret_cast<const short*>(zn);

  // A fragments: 2 row-frags x 4 k-chunks, registers for whole kernel.
  // A layout (16x16x32): row = lane&15, k = 8*(lane>>4)+e (+32*chunk)
  short8 a[2][4];
  #pragma unroll
  for (int rf = 0; rf < 2; ++rf) {
    int arow = rowBase + 32 * w + 16 * rf + lo;
    const short* p = znS + (size_t)arow * DD + 8 * hi;
    #pragma unroll
    for (int c = 0; c < 4; ++c)
      a[rf][c] = *reinterpret_cast<const short8*>(p + 32 * c);
  }

  float posv[2][4];
  float sume[2][4];
  int cntv[2][4];
  #pragma unroll
  for (int rf = 0; rf < 2; ++rf)
    #pragma unroll
    for (int r = 0; r < 4; ++r) {
      // C/D layout: col = lane&15, row = 4*(lane>>4)+reg  [m89/m91]
      posv[rf][r] = posh[rowBase + 32 * w + 16 * rf + 4 * hi + r];
      sume[rf][r] = 0.0f;
      cntv[rf][r] = 0;
    }

  #pragma unroll
  for (int it = 0; it < COL_ITERS; ++it) {
    int col0 = colBase + 64 * it;
    #pragma unroll
    for (int cf = 0; cf < 4; ++cf) {
      int bcol = col0 + 16 * cf + lo;
      const short* p = znS + (size_t)bcol * DD + 8 * hi;
      short8 b[4];
      #pragma unroll
      for (int c = 0; c < 4; ++c)
        b[c] = *reinterpret_cast<const short8*>(p + 32 * c);
      #pragma unroll
      for (int rf = 0; rf < 2; ++rf) {
        f32x4 acc = {0.0f, 0.0f, 0.0f, 0.0f};
        #pragma unroll
        for (int c = 0; c < 4; ++c)
          acc = __builtin_amdgcn_mfma_f32_16x16x32_bf16(a[rf][c], b[c], acc,
                                                        0, 0, 0);
        #pragma unroll
        for (int r = 0; r < 4; ++r) {
          float s = acc[r];               // dot (= sim/2)
          sume[rf][r] += __expf(s + s);   // exp(sim)
          cntv[rf][r] += (posv[rf][r] > s) ? 1 : 0;
        }
      }
    }
  }

  // reduce across the 16 lanes (bits 0..3) that share a row
  #pragma unroll
  for (int rf = 0; rf < 2; ++rf)
    #pragma unroll
    for (int r = 0; r < 4; ++r) {
      float v = sume[rf][r];
      int c2 = cntv[rf][r];
      #pragma unroll
      for (int m = 1; m < 16; m <<= 1) {
        v += __shfl_xor(v, m, 64);
        c2 += __shfl_xor(c2, m, 64);
      }
      if (lo == 0) {
        int row = rowBase + 32 * w + 16 * rf + 4 * hi + r;
        atomicAdd(&rowsum[row], v);
        atomicAdd(&rowcnt[row], c2);
      }
    }
}

// ---- kernel 3: finalize ----------------------------------------------------
__global__ __launch_bounds__(1024) void finalize_kernel(
    const float* __restrict__ rowsum, const int* __restrict__ rowcnt,
    const float* __restrict__ posh, const float* __restrict__ sd,
    float* __restrict__ out) {
  int tid = threadIdx.x;
  float lsum = 0.0f;
  unsigned int csum = 0;
  #pragma unroll
  for (int k = 0; k < NN / 1024; ++k) {
    int i = tid + k * 1024;
    float diag = __expf(sd[i] + sd[i]);       // exp(sim_ii)
    float lse = logf(rowsum[i] - diag);       // exclude diagonal
    lsum += lse - 2.0f * posh[i];             // lse_i - pos_i
    csum += (unsigned int)rowcnt[i];
  }
  #pragma unroll
  for (int m = 1; m < 64; m <<= 1) {
    lsum += __shfl_xor(lsum, m, 64);
    csum += __shfl_xor(csum, m, 64);
  }
  __shared__ float ls[16];
  __shared__ unsigned int cs[16];
  int w = tid >> 6, lane = tid & 63;
  if (lane == 0) { ls[w] = lsum; cs[w] = csum; }
  __syncthreads();
  if (tid == 0) {
    float L = 0.0f;
    unsigned long long C = 0;
    #pragma unroll
    for (int k = 0; k < 16; ++k) { L += ls[k]; C += cs[k]; }
    out[0] = L / (float)NN;
    out[1] = (float)((double)C / ((double)NN * (double)NN));
  }
}

extern "C" void kernel_launch(void* const* d_in, const int* in_sizes, int n_in,
                              void* d_out, int out_size, void* d_ws,
                              size_t ws_size, hipStream_t stream) {
  const float* zi = (const float*)d_in[0];
  const float* zj = (const float*)d_in[1];
  float* out = (float*)d_out;

  __hip_bfloat16* zn = (__hip_bfloat16*)d_ws;                  // 2 MB
  float* posh = (float*)((char*)d_ws + (size_t)NN * DD * 2);   // 32 KB each
  float* sd = posh + NN;
  float* rowsum = sd + NN;
  int* rowcnt = (int*)(rowsum + NN);

  prep_kernel<<<BB, 128, 0, stream>>>(zi, zj, zn, posh, sd, rowsum, rowcnt);
  main_kernel<<<dim3(NN / ROWS_PER_BLOCK, COLSPLIT), 256, 0, stream>>>(
      zn, posh, rowsum, rowcnt);
  finalize_kernel<<<1, 1024, 0, stream>>>(rowsum, rowcnt, posh, sd, out);
}

// Round 5
// 134.733 us; speedup vs baseline: 2.2230x; 2.2230x over previous
//
#include <hip/hip_runtime.h>
#include <hip/hip_bf16.h>

#define NN 8192
#define DD 128
#define BB 4096

#define ROWS_PER_BLOCK 128   // 4 waves * 2 rowfrags * 16
#define COLSPLIT 32
#define COLS_PER_BLOCK (NN / COLSPLIT)   // 256
#define COL_ITERS (COLS_PER_BLOCK / 64)  // 4

typedef __attribute__((ext_vector_type(8))) short short8;
typedef __attribute__((ext_vector_type(4))) float f32x4;

// ---- kernel 1: normalize rows -> bf16, pos dot, self dot, zero accums -----
// One block = row pair (r, r+BB). Wave 0 handles r (from z_i), wave 1 r+BB.
__global__ __launch_bounds__(128) void prep_kernel(
    const float* __restrict__ zi, const float* __restrict__ zj,
    __hip_bfloat16* __restrict__ zn, float* __restrict__ posh,
    float* __restrict__ sd, float* __restrict__ rowsum,
    int* __restrict__ rowcnt) {
  int r0 = blockIdx.x;
  int w = threadIdx.x >> 6;
  int lane = threadIdx.x & 63;
  int row = r0 + w * BB;
  const float* src = (w ? zj : zi) + (size_t)r0 * DD;
  float2 v = *reinterpret_cast<const float2*>(src + lane * 2);
  float ss = v.x * v.x + v.y * v.y;
  #pragma unroll
  for (int m = 1; m < 64; m <<= 1) ss += __shfl_xor(ss, m, 64);
  float inv = 1.0f / fmaxf(sqrtf(ss), 1e-8f);
  __hip_bfloat16 b0 = __float2bfloat16(v.x * inv);
  __hip_bfloat16 b1 = __float2bfloat16(v.y * inv);
  *reinterpret_cast<__hip_bfloat162*>(zn + (size_t)row * DD + lane * 2) =
      __hip_bfloat162{b0, b1};
  // bf16-rounded values (consistent with what main_kernel's MFMA consumes)
  float f0 = __bfloat162float(b0), f1 = __bfloat162float(b1);
  float sq = f0 * f0 + f1 * f1;
  __shared__ float sb[2][DD];
  sb[w][2 * lane] = f0;
  sb[w][2 * lane + 1] = f1;
  __syncthreads();
  float o0 = sb[w ^ 1][2 * lane], o1 = sb[w ^ 1][2 * lane + 1];
  float dp = f0 * o0 + f1 * o1;
  #pragma unroll
  for (int m = 1; m < 64; m <<= 1) {
    sq += __shfl_xor(sq, m, 64);
    dp += __shfl_xor(dp, m, 64);
  }
  if (lane == 0) {
    sd[row] = sq;
    posh[row] = dp;     // symmetric: same value for both rows of the pair
    rowsum[row] = 0.0f;
    rowcnt[row] = 0;
  }
}

// ---- kernel 2: fused sim GEMM + exp-rowsum + count ------------------------
__global__ __launch_bounds__(256) void main_kernel(
    const __hip_bfloat16* __restrict__ zn, const float* __restrict__ posh,
    float* __restrict__ rowsum, int* __restrict__ rowcnt) {
  int w = threadIdx.x >> 6;
  int lane = threadIdx.x & 63;
  int lo = lane & 15, hi = lane >> 4;
  int rowBase = blockIdx.x * ROWS_PER_BLOCK;
  int colBase = blockIdx.y * COLS_PER_BLOCK;

  const short* znS = reinterpret_cast<const short*>(zn);

  // A fragments: 2 row-frags x 4 k-chunks, registers for whole kernel.
  // A layout (16x16x32): row = lane&15, k = 8*(lane>>4)+e (+32*chunk)
  short8 a[2][4];
  #pragma unroll
  for (int rf = 0; rf < 2; ++rf) {
    int arow = rowBase + 32 * w + 16 * rf + lo;
    const short* p = znS + (size_t)arow * DD + 8 * hi;
    #pragma unroll
    for (int c = 0; c < 4; ++c)
      a[rf][c] = *reinterpret_cast<const short8*>(p + 32 * c);
  }

  float posv[2][4];
  float sume[2][4];
  int cntv[2][4];
  #pragma unroll
  for (int rf = 0; rf < 2; ++rf)
    #pragma unroll
    for (int r = 0; r < 4; ++r) {
      // C/D layout: col = lane&15, row = 4*(lane>>4)+reg  [m89/m91]
      posv[rf][r] = posh[rowBase + 32 * w + 16 * rf + 4 * hi + r];
      sume[rf][r] = 0.0f;
      cntv[rf][r] = 0;
    }

  #pragma unroll
  for (int it = 0; it < COL_ITERS; ++it) {
    int col0 = colBase + 64 * it;
    #pragma unroll
    for (int cf = 0; cf < 4; ++cf) {
      int bcol = col0 + 16 * cf + lo;
      const short* p = znS + (size_t)bcol * DD + 8 * hi;
      short8 b[4];
      #pragma unroll
      for (int c = 0; c < 4; ++c)
        b[c] = *reinterpret_cast<const short8*>(p + 32 * c);
      #pragma unroll
      for (int rf = 0; rf < 2; ++rf) {
        f32x4 acc = {0.0f, 0.0f, 0.0f, 0.0f};
        #pragma unroll
        for (int c = 0; c < 4; ++c)
          acc = __builtin_amdgcn_mfma_f32_16x16x32_bf16(a[rf][c], b[c], acc,
                                                        0, 0, 0);
        #pragma unroll
        for (int r = 0; r < 4; ++r) {
          float s = acc[r];               // dot (= sim/2)
          sume[rf][r] += __expf(s + s);   // exp(sim)
          cntv[rf][r] += (posv[rf][r] > s) ? 1 : 0;
        }
      }
    }
  }

  // reduce across the 16 lanes (bits 0..3) that share a row
  #pragma unroll
  for (int rf = 0; rf < 2; ++rf)
    #pragma unroll
    for (int r = 0; r < 4; ++r) {
      float v = sume[rf][r];
      int c2 = cntv[rf][r];
      #pragma unroll
      for (int m = 1; m < 16; m <<= 1) {
        v += __shfl_xor(v, m, 64);
        c2 += __shfl_xor(c2, m, 64);
      }
      if (lo == 0) {
        int row = rowBase + 32 * w + 16 * rf + 4 * hi + r;
        atomicAdd(&rowsum[row], v);
        atomicAdd(&rowcnt[row], c2);
      }
    }
}

// ---- kernel 3: finalize ----------------------------------------------------
__global__ __launch_bounds__(1024) void finalize_kernel(
    const float* __restrict__ rowsum, const int* __restrict__ rowcnt,
    const float* __restrict__ posh, const float* __restrict__ sd,
    float* __restrict__ out) {
  int tid = threadIdx.x;
  float lsum = 0.0f;
  unsigned int csum = 0;
  #pragma unroll
  for (int k = 0; k < NN / 1024; ++k) {
    int i = tid + k * 1024;
    float diag = __expf(sd[i] + sd[i]);       // exp(sim_ii)
    float lse = logf(rowsum[i] - diag);       // exclude diagonal
    lsum += lse - 2.0f * posh[i];             // lse_i - pos_i
    csum += (unsigned int)rowcnt[i];
  }
  #pragma unroll
  for (int m = 1; m < 64; m <<= 1) {
    lsum += __shfl_xor(lsum, m, 64);
    csum += __shfl_xor(csum, m, 64);
  }
  __shared__ float ls[16];
  __shared__ unsigned int cs[16];
  int w = tid >> 6, lane = tid & 63;
  if (lane == 0) { ls[w] = lsum; cs[w] = csum; }
  __syncthreads();
  if (tid == 0) {
    float L = 0.0f;
    unsigned long long C = 0;
    #pragma unroll
    for (int k = 0; k < 16; ++k) { L += ls[k]; C += cs[k]; }
    out[0] = L / (float)NN;
    out[1] = (float)((double)C / ((double)NN * (double)NN));
  }
}

extern "C" void kernel_launch(void* const* d_in, const int* in_sizes, int n_in,
                              void* d_out, int out_size, void* d_ws,
                              size_t ws_size, hipStream_t stream) {
  const float* zi = (const float*)d_in[0];
  const float* zj = (const float*)d_in[1];
  float* out = (float*)d_out;

  __hip_bfloat16* zn = (__hip_bfloat16*)d_ws;                  // 2 MB
  float* posh = (float*)((char*)d_ws + (size_t)NN * DD * 2);   // 32 KB each
  float* sd = posh + NN;
  float* rowsum = sd + NN;
  int* rowcnt = (int*)(rowsum + NN);

  prep_kernel<<<BB, 128, 0, stream>>>(zi, zj, zn, posh, sd, rowsum, rowcnt);
  main_kernel<<<dim3(NN / ROWS_PER_BLOCK, COLSPLIT), 256, 0, stream>>>(
      zn, posh, rowsum, rowcnt);
  finalize_kernel<<<1, 1024, 0, stream>>>(rowsum, rowcnt, posh, sd, out);
}

// Round 6
// 130.471 us; speedup vs baseline: 2.2956x; 1.0327x over previous
//
#include <hip/hip_runtime.h>
#include <hip/hip_bf16.h>

#define NN 8192
#define DD 128
#define BB 4096

#define ROWS_PER_BLOCK 256           // 4 waves * 64 rows
#define COLSPLIT 16
#define COLS_PER_BLOCK (NN / COLSPLIT)   // 512
#define TILES (COLS_PER_BLOCK / 64)      // 8 tiles of 64 cols

typedef __attribute__((ext_vector_type(8))) short short8;
typedef __attribute__((ext_vector_type(4))) float f32x4;

typedef __attribute__((address_space(3))) unsigned lds_u32;
typedef __attribute__((address_space(1))) unsigned glb_u32;

// ---- kernel 1: normalize rows -> bf16, pos dot, self dot, zero accums -----
__global__ __launch_bounds__(128) void prep_kernel(
    const float* __restrict__ zi, const float* __restrict__ zj,
    __hip_bfloat16* __restrict__ zn, float* __restrict__ posh,
    float* __restrict__ sd, float* __restrict__ rowsum,
    int* __restrict__ rowcnt, unsigned* __restrict__ done) {
  int r0 = blockIdx.x;
  int w = threadIdx.x >> 6;
  int lane = threadIdx.x & 63;
  int row = r0 + w * BB;
  if (r0 == 0 && threadIdx.x == 0) *done = 0;
  const float* src = (w ? zj : zi) + (size_t)r0 * DD;
  float2 v = *reinterpret_cast<const float2*>(src + lane * 2);
  float ss = v.x * v.x + v.y * v.y;
  #pragma unroll
  for (int m = 1; m < 64; m <<= 1) ss += __shfl_xor(ss, m, 64);
  float inv = 1.0f / fmaxf(sqrtf(ss), 1e-8f);
  __hip_bfloat16 b0 = __float2bfloat16(v.x * inv);
  __hip_bfloat16 b1 = __float2bfloat16(v.y * inv);
  *reinterpret_cast<__hip_bfloat162*>(zn + (size_t)row * DD + lane * 2) =
      __hip_bfloat162{b0, b1};
  // bf16-rounded values (consistent with what main_kernel's MFMA consumes)
  float f0 = __bfloat162float(b0), f1 = __bfloat162float(b1);
  float sq = f0 * f0 + f1 * f1;
  __shared__ float sb[2][DD];
  sb[w][2 * lane] = f0;
  sb[w][2 * lane + 1] = f1;
  __syncthreads();
  float o0 = sb[w ^ 1][2 * lane], o1 = sb[w ^ 1][2 * lane + 1];
  float dp = f0 * o0 + f1 * o1;
  #pragma unroll
  for (int m = 1; m < 64; m <<= 1) {
    sq += __shfl_xor(sq, m, 64);
    dp += __shfl_xor(dp, m, 64);
  }
  if (lane == 0) {
    sd[row] = sq;
    posh[row] = dp;     // = sim_pos/2
    rowsum[row] = 0.0f;
    rowcnt[row] = 0;
  }
}

// ---- kernel 2: fused sim GEMM + exp-rowsum + count + last-block finalize --
__global__ __launch_bounds__(256) void main_kernel(
    const __hip_bfloat16* __restrict__ zn, const float* __restrict__ posh,
    const float* __restrict__ sd, float* __restrict__ rowsum,
    int* __restrict__ rowcnt, unsigned* __restrict__ done,
    float* __restrict__ out) {
  __shared__ char ldsbuf[2][16384];   // double-buffered 64-col x 128-k bf16 tile
  __shared__ float redf[4];
  __shared__ unsigned redc[4];
  __shared__ int amLast;

  const int tid = threadIdx.x;
  const int w = tid >> 6;
  const int lane = tid & 63;
  const int lo = lane & 15, hi = lane >> 4;
  const int rowBase = blockIdx.x * ROWS_PER_BLOCK;
  const int colBase = blockIdx.y * COLS_PER_BLOCK;
  const short* znS = reinterpret_cast<const short*>(zn);

  // Staging: tile buffer layout [col][chunk] with chunk (16B) XOR-swizzled by
  // (col&7). global_load_lds writes linearly (base + lane*16), so the swizzle
  // is applied on the SOURCE address (rule 21): lane writes phys chunk
  // (lane&15) of col 4s+(lane>>4); source = logical chunk phys^(col&7).
  #define STAGE(bufidx, gcol0)                                               \
    {                                                                        \
      _Pragma("unroll")                                                      \
      for (int q = 0; q < 4; ++q) {                                          \
        int s_ = 4 * w + q;                                                  \
        int coll_ = 4 * s_ + (lane >> 4);                                    \
        int lc_ = (lane & 15) ^ (coll_ & 7);                                 \
        const short* src_ = znS + (size_t)((gcol0) + coll_) * DD + lc_ * 8;  \
        __builtin_amdgcn_global_load_lds(                                    \
            (const glb_u32*)src_, (lds_u32*)(&ldsbuf[bufidx][s_ * 1024]),    \
            16, 0, 0);                                                       \
      }                                                                      \
    }

  // prologue: stage tile 0, then load A fragments + posv (all drained by the
  // first __syncthreads)
  STAGE(0, colBase);

  // A fragments: 4 row-frags x 4 k-chunks, registers for whole kernel.
  // A layout (16x16x32): row = lane&15, k = 8*(lane>>4)+e (+32*chunk)
  short8 a[4][4];
  #pragma unroll
  for (int rf = 0; rf < 4; ++rf) {
    int arow = rowBase + 64 * w + 16 * rf + lo;
    const short* p = znS + (size_t)arow * DD + 8 * hi;
    #pragma unroll
    for (int c = 0; c < 4; ++c)
      a[rf][c] = *reinterpret_cast<const short8*>(p + 32 * c);
  }

  float posv[4][4];
  float sume[4][4];
  int cntv[4][4];
  #pragma unroll
  for (int rf = 0; rf < 4; ++rf)
    #pragma unroll
    for (int r = 0; r < 4; ++r) {
      // C/D layout: col = lane&15, row = 4*(lane>>4)+reg  [m89/m91]
      posv[rf][r] = posh[rowBase + 64 * w + 16 * rf + 4 * hi + r];
      sume[rf][r] = 0.0f;
      cntv[rf][r] = 0;
    }

  __syncthreads();   // tile 0 staged (vmcnt(0) drain), A/posv in regs

  #pragma unroll 2
  for (int t = 0; t < TILES; ++t) {
    if (t + 1 < TILES) STAGE((t + 1) & 1, colBase + (t + 1) * 64);
    #pragma unroll
    for (int cf = 0; cf < 4; ++cf) {
      short8 b[4];
      #pragma unroll
      for (int c = 0; c < 4; ++c) {
        int coll = 16 * cf + lo;
        int off = coll * 256 + 16 * ((hi + 4 * c) ^ (lo & 7));
        b[c] = *reinterpret_cast<const short8*>(&ldsbuf[t & 1][off]);
      }
      #pragma unroll
      for (int rf = 0; rf < 4; ++rf) {
        f32x4 acc = {0.0f, 0.0f, 0.0f, 0.0f};
        #pragma unroll
        for (int c = 0; c < 4; ++c)
          acc = __builtin_amdgcn_mfma_f32_16x16x32_bf16(a[rf][c], b[c], acc,
                                                        0, 0, 0);
        #pragma unroll
        for (int r = 0; r < 4; ++r) {
          float s = acc[r];               // dot (= sim/2)
          sume[rf][r] += __expf(s + s);   // exp(sim)
          cntv[rf][r] += (posv[rf][r] > s) ? 1 : 0;
        }
      }
    }
    __syncthreads();   // drains next-tile staging; protects buffer overwrite
  }

  // reduce across the 16 lanes (bits 0..3) that share a row, then atomics
  #pragma unroll
  for (int rf = 0; rf < 4; ++rf)
    #pragma unroll
    for (int r = 0; r < 4; ++r) {
      float v = sume[rf][r];
      int c2 = cntv[rf][r];
      #pragma unroll
      for (int m = 1; m < 16; m <<= 1) {
        v += __shfl_xor(v, m, 64);
        c2 += __shfl_xor(c2, m, 64);
      }
      if (lo == 0) {
        int row = rowBase + 64 * w + 16 * rf + 4 * hi + r;
        atomicAdd(&rowsum[row], v);
        atomicAdd(&rowcnt[row], c2);
      }
    }

  // ---- last block finalizes (saves one kernel launch) ----
  __threadfence();
  if (tid == 0) {
    unsigned prev = atomicAdd(done, 1u);
    amLast = (prev == gridDim.x * gridDim.y - 1) ? 1 : 0;
  }
  __syncthreads();
  if (amLast) {
    float lsum = 0.0f;
    unsigned csum = 0;
    for (int k = 0; k < NN / 256; ++k) {
      int i = tid + k * 256;
      float rs = atomicAdd(&rowsum[i], 0.0f);   // coherent read (cross-XCD)
      int rc = atomicAdd(&rowcnt[i], 0);
      float diag = __expf(sd[i] + sd[i]);       // exp(sim_ii)
      lsum += logf(rs - diag) - 2.0f * posh[i]; // lse_i - pos_i
      csum += (unsigned)rc;
    }
    #pragma unroll
    for (int m = 1; m < 64; m <<= 1) {
      lsum += __shfl_xor(lsum, m, 64);
      csum += __shfl_xor(csum, m, 64);
    }
    if (lane == 0) { redf[w] = lsum; redc[w] = csum; }
    __syncthreads();
    if (tid == 0) {
      float L = redf[0] + redf[1] + redf[2] + redf[3];
      unsigned long long C =
          (unsigned long long)redc[0] + redc[1] + redc[2] + redc[3];
      out[0] = L / (float)NN;
      out[1] = (float)((double)C / ((double)NN * (double)NN));
    }
  }
}

extern "C" void kernel_launch(void* const* d_in, const int* in_sizes, int n_in,
                              void* d_out, int out_size, void* d_ws,
                              size_t ws_size, hipStream_t stream) {
  const float* zi = (const float*)d_in[0];
  const float* zj = (const float*)d_in[1];
  float* out = (float*)d_out;

  __hip_bfloat16* zn = (__hip_bfloat16*)d_ws;                  // 2 MB
  float* posh = (float*)((char*)d_ws + (size_t)NN * DD * 2);   // 32 KB each
  float* sd = posh + NN;
  float* rowsum = sd + NN;
  int* rowcnt = (int*)(rowsum + NN);
  unsigned* done = (unsigned*)(rowcnt + NN);

  prep_kernel<<<BB, 128, 0, stream>>>(zi, zj, zn, posh, sd, rowsum, rowcnt,
                                      done);
  main_kernel<<<dim3(NN / ROWS_PER_BLOCK, COLSPLIT), 256, 0, stream>>>(
      zn, posh, sd, rowsum, rowcnt, done, out);
}

// Round 10
// 98.541 us; speedup vs baseline: 3.0394x; 1.3240x over previous
//
#include <hip/hip_runtime.h>
#include <hip/hip_bf16.h>

#define NN 8192
#define DD 128
#define BB 4096

#define ROWS_PER_BLOCK 128           // 4 waves * 32 rows (2 rowfrags)
#define COLSPLIT 16
#define COLS_PER_BLOCK (NN / COLSPLIT)   // 512
#define TILES (COLS_PER_BLOCK / 64)      // 8 tiles of 64 cols

typedef __attribute__((ext_vector_type(8))) short short8;
typedef __attribute__((ext_vector_type(4))) float f32x4;

typedef __attribute__((address_space(3))) unsigned lds_u32;
typedef __attribute__((address_space(1))) unsigned glb_u32;

// ---- kernel 1: normalize rows -> bf16, pos dot, self dot, zero accums -----
__global__ __launch_bounds__(128) void prep_kernel(
    const float* __restrict__ zi, const float* __restrict__ zj,
    __hip_bfloat16* __restrict__ zn, float* __restrict__ posh,
    float* __restrict__ sd, float* __restrict__ rowsum,
    int* __restrict__ rowcnt) {
  int r0 = blockIdx.x;
  int w = threadIdx.x >> 6;
  int lane = threadIdx.x & 63;
  int row = r0 + w * BB;
  const float* src = (w ? zj : zi) + (size_t)r0 * DD;
  float2 v = *reinterpret_cast<const float2*>(src + lane * 2);
  float ss = v.x * v.x + v.y * v.y;
  #pragma unroll
  for (int m = 1; m < 64; m <<= 1) ss += __shfl_xor(ss, m, 64);
  float inv = 1.0f / fmaxf(sqrtf(ss), 1e-8f);
  __hip_bfloat16 b0 = __float2bfloat16(v.x * inv);
  __hip_bfloat16 b1 = __float2bfloat16(v.y * inv);
  *reinterpret_cast<__hip_bfloat162*>(zn + (size_t)row * DD + lane * 2) =
      __hip_bfloat162{b0, b1};
  // bf16-rounded values (consistent with what main_kernel's MFMA consumes)
  float f0 = __bfloat162float(b0), f1 = __bfloat162float(b1);
  float sq = f0 * f0 + f1 * f1;
  __shared__ float sb[2][DD];
  sb[w][2 * lane] = f0;
  sb[w][2 * lane + 1] = f1;
  __syncthreads();
  float o0 = sb[w ^ 1][2 * lane], o1 = sb[w ^ 1][2 * lane + 1];
  float dp = f0 * o0 + f1 * o1;
  #pragma unroll
  for (int m = 1; m < 64; m <<= 1) {
    sq += __shfl_xor(sq, m, 64);
    dp += __shfl_xor(dp, m, 64);
  }
  if (lane == 0) {
    sd[row] = sq;
    posh[row] = dp;     // = sim_pos/2
    rowsum[row] = 0.0f;
    rowcnt[row] = 0;
  }
}

// ---- kernel 2: fused sim GEMM + exp-rowsum + count ------------------------
__global__ __launch_bounds__(256) void main_kernel(
    const __hip_bfloat16* __restrict__ zn, const float* __restrict__ posh,
    float* __restrict__ rowsum, int* __restrict__ rowcnt) {
  __shared__ char ldsbuf[2][16384];   // double-buffered 64-col x 128-k bf16 tile

  const int tid = threadIdx.x;
  const int w = tid >> 6;
  const int lane = tid & 63;
  const int lo = lane & 15, hi = lane >> 4;
  const int rowBase = blockIdx.x * ROWS_PER_BLOCK;
  const int colBase = blockIdx.y * COLS_PER_BLOCK;
  const short* znS = reinterpret_cast<const short*>(zn);

  // Staging: tile buffer layout [col][chunk] with 16B chunk XOR-swizzled by
  // (col&7). global_load_lds writes linearly (base + lane*16), so the swizzle
  // is applied on the SOURCE address (rule 21): lane writes phys chunk
  // (lane&15) of col 4s+(lane>>4); source = logical chunk phys^(col&7).
  #define STAGE(bufidx, gcol0)                                               \
    {                                                                        \
      _Pragma("unroll")                                                      \
      for (int q = 0; q < 4; ++q) {                                          \
        int s_ = 4 * w + q;                                                  \
        int coll_ = 4 * s_ + (lane >> 4);                                    \
        int lc_ = (lane & 15) ^ (coll_ & 7);                                 \
        const short* src_ = znS + (size_t)((gcol0) + coll_) * DD + lc_ * 8;  \
        __builtin_amdgcn_global_load_lds(                                    \
            (const glb_u32*)src_, (lds_u32*)(&ldsbuf[bufidx][s_ * 1024]),    \
            16, 0, 0);                                                       \
      }                                                                      \
    }

  // prologue: stage tile 0, then load A fragments + posv (all drained by the
  // first __syncthreads)
  STAGE(0, colBase);

  // A fragments: 2 row-frags x 4 k-chunks, registers for whole kernel.
  // A layout (16x16x32): row = lane&15, k = 8*(lane>>4)+e (+32*chunk)
  short8 a[2][4];
  #pragma unroll
  for (int rf = 0; rf < 2; ++rf) {
    int arow = rowBase + 32 * w + 16 * rf + lo;
    const short* p = znS + (size_t)arow * DD + 8 * hi;
    #pragma unroll
    for (int c = 0; c < 4; ++c)
      a[rf][c] = *reinterpret_cast<const short8*>(p + 32 * c);
  }

  float posv[2][4];
  float sume[2][4];
  int cntv[2][4];
  #pragma unroll
  for (int rf = 0; rf < 2; ++rf)
    #pragma unroll
    for (int r = 0; r < 4; ++r) {
      // C/D layout: col = lane&15, row = 4*(lane>>4)+reg  [m89/m91]
      posv[rf][r] = posh[rowBase + 32 * w + 16 * rf + 4 * hi + r];
      sume[rf][r] = 0.0f;
      cntv[rf][r] = 0;
    }

  __syncthreads();   // tile 0 staged (vmcnt(0) drain), A/posv in regs

  #pragma unroll 2
  for (int t = 0; t < TILES; ++t) {
    if (t + 1 < TILES) STAGE((t + 1) & 1, colBase + (t + 1) * 64);
    #pragma unroll
    for (int cf = 0; cf < 4; ++cf) {
      short8 b[4];
      #pragma unroll
      for (int c = 0; c < 4; ++c) {
        int coll = 16 * cf + lo;
        int off = coll * 256 + 16 * ((hi + 4 * c) ^ (lo & 7));
        b[c] = *reinterpret_cast<const short8*>(&ldsbuf[t & 1][off]);
      }
      #pragma unroll
      for (int rf = 0; rf < 2; ++rf) {
        f32x4 acc = {0.0f, 0.0f, 0.0f, 0.0f};
        #pragma unroll
        for (int c = 0; c < 4; ++c)
          acc = __builtin_amdgcn_mfma_f32_16x16x32_bf16(a[rf][c], b[c], acc,
                                                        0, 0, 0);
        #pragma unroll
        for (int r = 0; r < 4; ++r) {
          float s = acc[r];               // dot (= sim/2)
          // exp(2s) = exp2(2*log2(e)*s): one v_mul + v_exp
          sume[rf][r] += exp2f(s * 2.885390082f);
          cntv[rf][r] += (posv[rf][r] > s) ? 1 : 0;
        }
      }
    }
    __syncthreads();   // drains next-tile staging; protects buffer overwrite
  }

  // reduce across the 16 lanes (bits 0..3) that share a row, then atomics
  #pragma unroll
  for (int rf = 0; rf < 2; ++rf)
    #pragma unroll
    for (int r = 0; r < 4; ++r) {
      float v = sume[rf][r];
      int c2 = cntv[rf][r];
      #pragma unroll
      for (int m = 1; m < 16; m <<= 1) {
        v += __shfl_xor(v, m, 64);
        c2 += __shfl_xor(c2, m, 64);
      }
      if (lo == 0) {
        int row = rowBase + 32 * w + 16 * rf + 4 * hi + r;
        atomicAdd(&rowsum[row], v);
        atomicAdd(&rowcnt[row], c2);
      }
    }
}

// ---- kernel 3: finalize ----------------------------------------------------
__global__ __launch_bounds__(1024) void finalize_kernel(
    const float* __restrict__ rowsum, const int* __restrict__ rowcnt,
    const float* __restrict__ posh, const float* __restrict__ sd,
    float* __restrict__ out) {
  int tid = threadIdx.x;
  float lsum = 0.0f;
  unsigned csum = 0;
  #pragma unroll
  for (int k = 0; k < NN / 1024; ++k) {
    int i = tid + k * 1024;
    float diag = __expf(sd[i] + sd[i]);       // exp(sim_ii)
    lsum += logf(rowsum[i] - diag) - 2.0f * posh[i];  // lse_i - pos_i
    csum += (unsigned)rowcnt[i];
  }
  #pragma unroll
  for (int m = 1; m < 64; m <<= 1) {
    lsum += __shfl_xor(lsum, m, 64);
    csum += __shfl_xor(csum, m, 64);
  }
  __shared__ float ls[16];
  __shared__ unsigned cs[16];
  int w = tid >> 6, lane = tid & 63;
  if (lane == 0) { ls[w] = lsum; cs[w] = csum; }
  __syncthreads();
  if (tid == 0) {
    float L = 0.0f;
    unsigned long long C = 0;
    #pragma unroll
    for (int k = 0; k < 16; ++k) { L += ls[k]; C += cs[k]; }
    out[0] = L / (float)NN;
    out[1] = (float)((double)C / ((double)NN * (double)NN));
  }
}

extern "C" void kernel_launch(void* const* d_in, const int* in_sizes, int n_in,
                              void* d_out, int out_size, void* d_ws,
                              size_t ws_size, hipStream_t stream) {
  const float* zi = (const float*)d_in[0];
  const float* zj = (const float*)d_in[1];
  float* out = (float*)d_out;

  __hip_bfloat16* zn = (__hip_bfloat16*)d_ws;                  // 2 MB
  float* posh = (float*)((char*)d_ws + (size_t)NN * DD * 2);   // 32 KB each
  float* sd = posh + NN;
  float* rowsum = sd + NN;
  int* rowcnt = (int*)(rowsum + NN);

  prep_kernel<<<BB, 128, 0, stream>>>(zi, zj, zn, posh, sd, rowsum, rowcnt);
  main_kernel<<<dim3(NN / ROWS_PER_BLOCK, COLSPLIT), 256, 0, stream>>>(
      zn, posh, rowsum, rowcnt);
  finalize_kernel<<<1, 1024, 0, stream>>>(rowsum, rowcnt, posh, sd, out);
}